// Round 6
// baseline (185.551 us; speedup 1.0000x reference)
//
#include <hip/hip_runtime.h>

// GraphSAGE layer: B=8, N=5000, E=100000, D=128. All float tensors f32; edge_index int32.
// R23 pipeline (3 dispatches, back to the proven R18 shell after two failed
// persistent-kernel rounds): memset(cnt) -> fill_k (XCD-affine u32 buckets
// {src:16|bf16(m):16} + x->bf16 + packW; R20's exact body) -> fused_k.
// fused_k change (single variable): the gather's scattered row reads now go through
// global_load_lds DMA (per-lane global addr, uniform LDS dest, 16B/lane) into a
// per-wave double-buffered LDS stage, vmcnt(8)-pipelined across the wave's 4 nodes,
// instead of per-lane VGPR-returning loads.
// Rationale: R17-R20 fused invariant at 44-47us across node-serial / group-parallel /
// chunk-masked / split-kernel gathers => per-CU scattered-load bound on the vector
// return path (12.5k lines/CU x ~400cy / ~64 outstanding ~= 33us, insensitive to
// ILP/TLP/segments). DMA staging is the one different hardware path; null => bound
// is fundamental and the next lever is fill_k.

#define B_ 8
#define N_ 5000
#define E_ 100000
#define D_ 128
#define EPS_ 1e-5f
#define NNODES (B_ * N_)   // 40000
#define JB 313             // 16-node blocks per batch (312*16+8 = 5000)
#define PPB ((E_ / 2 + 255) / 256)    // 196 pair-blocks per batch (E even)
#define FILL_BLOCKS (8 * PPB)         // 1568
#define CONV_BLOCKS 2500              // x -> bf16: 2048 elems/block
#define CAP 64             // bucket capacity per node (avg deg 20, P(ovf) ~ 5e-14)
#define LDSP 136           // padded bf16 row stride (272 B -> 2-way bank alias, free)

typedef __bf16 bf16x8 __attribute__((ext_vector_type(8)));
typedef float  f32x4  __attribute__((ext_vector_type(4)));

static __device__ __forceinline__ unsigned short f2bf(float f) {
    union { float f; unsigned int i; } c; c.f = f;
    unsigned int i = c.i;
    i += 0x7fffu + ((i >> 16) & 1u);
    return (unsigned short)(i >> 16);
}
static __device__ __forceinline__ float bflo(unsigned int u) {
    return __uint_as_float(u << 16);
}
static __device__ __forceinline__ float bfhi(unsigned int u) {
    return __uint_as_float(u & 0xffff0000u);
}

// Async global->LDS DMA, 16B per lane. Global addr is PER-LANE; LDS dest is the
// wave-uniform base: lane L's 16B lands at base + L*16.
static __device__ __forceinline__ void dma16(const unsigned short* g,
                                             unsigned short* l) {
    __builtin_amdgcn_global_load_lds(
        (const __attribute__((address_space(1))) unsigned int*)g,
        (__attribute__((address_space(3))) unsigned int*)l,
        16, 0, 0);
}
// Counted waits; "memory" clobber + sched_barrier(0) pin LDS reads behind the wait.
#define WAITVM8() do { asm volatile("s_waitcnt vmcnt(8)" ::: "memory"); \
                       __builtin_amdgcn_sched_barrier(0); } while (0)
#define WAITVM0() do { asm volatile("s_waitcnt vmcnt(0)" ::: "memory"); \
                       __builtin_amdgcn_sched_barrier(0); } while (0)

// ---------- fill: XCD-affine u32 buckets (0..1567) + x->bf16 (..4067) + packW ----------
__global__ __launch_bounds__(256) void fill_k(
    const int* __restrict__ ei, const float* __restrict__ em,
    int* __restrict__ cnt, unsigned int* __restrict__ entries,
    const float* __restrict__ x, unsigned short* __restrict__ xbf,
    const float* __restrict__ Wself, const float* __restrict__ Wnb,
    unsigned short* __restrict__ Bt)
{
    int blk = blockIdx.x;
    if (blk < FILL_BLOCKS) {
        int b = blk & 7;                    // batch -> XCD (round-robin dispatch)
        int p = (blk >> 3) * 256 + threadIdx.x;
        if (p >= E_ / 2) return;
        int e = 2 * p;                      // pair e, e+1 (E even -> both valid)
        const int* eib = ei + (size_t)b * 2 * E_;
        int2   sv = *(const int2*)(eib + e);
        int2   tv = *(const int2*)(eib + E_ + e);
        float2 mv = *(const float2*)(em + (size_t)b * E_ + e);
        int gb = b * N_;
        int g0 = gb + tv.x, g1 = gb + tv.y;
        int e0 = (mv.x != 0.0f), e1 = (mv.y != 0.0f);
        int s0 = atomicAdd(&cnt[g0], e0);
        int s1 = atomicAdd(&cnt[g1], e1);
        if (e0 && s0 < CAP)
            entries[((size_t)g0 << 6) + s0] =
                (unsigned int)(gb + sv.x) | ((unsigned int)f2bf(mv.x) << 16);
        if (e1 && s1 < CAP)
            entries[((size_t)g1 << 6) + s1] =
                (unsigned int)(gb + sv.y) | ((unsigned int)f2bf(mv.y) << 16);
    } else if (blk < FILL_BLOCKS + CONV_BLOCKS) {
        size_t base = (size_t)(blk - FILL_BLOCKS) * 2048 + threadIdx.x * 8;
        float4 va = *(const float4*)(x + base);
        float4 vb = *(const float4*)(x + base + 4);
        uint4 o;
        o.x = (unsigned int)f2bf(va.x) | ((unsigned int)f2bf(va.y) << 16);
        o.y = (unsigned int)f2bf(va.z) | ((unsigned int)f2bf(va.w) << 16);
        o.z = (unsigned int)f2bf(vb.x) | ((unsigned int)f2bf(vb.y) << 16);
        o.w = (unsigned int)f2bf(vb.z) | ((unsigned int)f2bf(vb.w) << 16);
        *(uint4*)(xbf + base) = o;
    } else {
        int n = blk - FILL_BLOCKS - CONV_BLOCKS;   // 0..127
        int k = threadIdx.x;                       // 0..255
        float v = (k < 128) ? Wself[(size_t)k * D_ + n]
                            : Wnb[(size_t)(k - 128) * D_ + n];
        Bt[(size_t)n * 256 + k] = f2bf(v);
    }
}

// ---------- fused: DMA-staged gather + MFMA GEMM + ReLU + LN + mask ----------
// Grid 8*JB; blk&7 = batch (XCD affinity), blk>>3 = 16-node group within batch.
// Wave wv owns rows wv*4..wv*4+3; per node: 8 dma16 stage 32 slots (4 rows/instr)
// into stage[wv][buf], double-buffered with vmcnt(8) across nodes.
__global__ __launch_bounds__(256) void fused_k(
    const unsigned short* __restrict__ xbf, const int* __restrict__ cnt,
    const unsigned int* __restrict__ entries,
    const unsigned short* __restrict__ Bt,
    const float* __restrict__ bself, const float* __restrict__ bnb,
    const float* __restrict__ gamma, const float* __restrict__ beta,
    const float* __restrict__ nmask, float* __restrict__ out)
{
    __shared__ unsigned short xs[16][LDSP];
    __shared__ unsigned short as[16][LDSP];
    __shared__ float red[4][2][16];
    __shared__ unsigned short stage[4][2][32][128];   // 64 KB: per-wave dbuf

    int t = threadIdx.x;
    int lane = t & 63, wv = t >> 6;
    int b = blockIdx.x & 7;
    int j = blockIdx.x >> 3;               // 0..JB-1
    int i0 = j * 16;
    int g0 = b * N_ + i0;
    int limit = N_ - i0; if (limit > 16) limit = 16;

    int sq = lane >> 4;                    // slot-within-quad (and DMA row group)
    int c8 = lane & 15;                    // 16B chunk within the 256B row

    // Metadata for this wave's 4 nodes (issued first; latency hides under xs stage).
    int dg4[4]; unsigned int ee4[4];
    #pragma unroll
    for (int i = 0; i < 4; ++i) {
        int row = wv * 4 + i;
        int gi = g0 + ((row < limit) ? row : 0);
        int d = cnt[gi]; if (d > CAP) d = CAP;
        dg4[i] = (row < limit) ? d : 0;
        ee4[i] = entries[((size_t)gi << 6) + lane];   // lane = slot 0..63
    }

    // Phase A1: stage own xbf rows into LDS (4 rows/wave, coalesced).
    #pragma unroll
    for (int lr = wv * 4; lr < wv * 4 + 4; ++lr) {
        unsigned int v = 0;
        if (lr < limit)
            v = ((const unsigned int*)(xbf + (size_t)(g0 + lr) * D_))[lane];
        ((unsigned int*)&xs[lr][0])[lane] = v;
    }

    // Stage node i's slots 0..31: instr q stages slots 4q..4q+3 (lane sq picks slot
    // 4q+sq, lands at stage[wv][BB][4q+sq][c8*8]). Masked slots -> hot row 0.
#define STAGE(I, BB) do {                                                     \
        _Pragma("unroll")                                                     \
        for (int q = 0; q < 8; ++q) {                                         \
            unsigned int ej = (unsigned int)__shfl((int)ee4[I], 4 * q + sq, 64); \
            int okq = (4 * q + sq) < dg4[I];                                  \
            int srow = okq ? (int)(ej & 0xffffu) : 0;                         \
            dma16(xbf + ((size_t)srow << 7) + (c8 << 3),                      \
                  &stage[wv][BB][4 * q][0]);                                  \
        }                                                                     \
    } while (0)

    STAGE(0, 0);

    #pragma unroll
    for (int i = 0; i < 4; ++i) {
        if (i == 0) STAGE(1, 1);
        else if (i == 1) STAGE(2, 0);
        else if (i == 2) STAGE(3, 1);

        if (i < 3) { WAITVM8(); } else { WAITVM0(); }

        // Accumulate node i from stage[wv][i&1].
        float a[8];
        #pragma unroll
        for (int z = 0; z < 8; ++z) a[z] = 0.f;
        float cs = 0.f;
        #pragma unroll
        for (int q = 0; q < 8; ++q) {
            unsigned int ej = (unsigned int)__shfl((int)ee4[i], 4 * q + sq, 64);
            int okq = (4 * q + sq) < dg4[i];
            float m = okq ? __uint_as_float(ej & 0xffff0000u) : 0.0f;
            uint4 v = *(const uint4*)&stage[wv][i & 1][4 * q + sq][c8 << 3];
            a[0] += bflo(v.x) * m; a[1] += bfhi(v.x) * m;
            a[2] += bflo(v.y) * m; a[3] += bfhi(v.y) * m;
            a[4] += bflo(v.z) * m; a[5] += bfhi(v.z) * m;
            a[6] += bflo(v.w) * m; a[7] += bfhi(v.w) * m;
            cs += m;
        }
        if (__builtin_expect(dg4[i] > 32, 0)) {       // rare tail: direct loads
            #pragma unroll 1
            for (int q = 8; q < 16; ++q) {
                if (4 * q >= dg4[i]) break;
                unsigned int ej = (unsigned int)__shfl((int)ee4[i], 4 * q + sq, 64);
                int okq = (4 * q + sq) < dg4[i];
                int sj = okq ? (int)(ej & 0xffffu) : 0;
                float m = okq ? __uint_as_float(ej & 0xffff0000u) : 0.0f;
                uint4 w = *(const uint4*)(xbf + ((size_t)sj << 7) + (c8 << 3));
                a[0] += bflo(w.x) * m; a[1] += bfhi(w.x) * m;
                a[2] += bflo(w.y) * m; a[3] += bfhi(w.y) * m;
                a[4] += bflo(w.z) * m; a[5] += bfhi(w.z) * m;
                a[6] += bflo(w.w) * m; a[7] += bfhi(w.w) * m;
                cs += m;
            }
        }

        // Reduce across the 4 slot-groups (sq = lane bits 4..5).
        #pragma unroll
        for (int z = 0; z < 8; ++z) {
            a[z] += __shfl_xor(a[z], 16, 64);
            a[z] += __shfl_xor(a[z], 32, 64);
        }
        cs += __shfl_xor(cs, 16, 64);
        cs += __shfl_xor(cs, 32, 64);

        if (lane < 16) {
            float inv = 1.0f / fmaxf(cs, 1.0f);
            uint4 o;
            o.x = (unsigned int)f2bf(a[0] * inv) | ((unsigned int)f2bf(a[1] * inv) << 16);
            o.y = (unsigned int)f2bf(a[2] * inv) | ((unsigned int)f2bf(a[3] * inv) << 16);
            o.z = (unsigned int)f2bf(a[4] * inv) | ((unsigned int)f2bf(a[5] * inv) << 16);
            o.w = (unsigned int)f2bf(a[6] * inv) | ((unsigned int)f2bf(a[7] * inv) << 16);
            *(uint4*)&as[wv * 4 + i][c8 << 3] = o;    // rows >= limit: dg=0 -> zeros
        }
    }
#undef STAGE
    __syncthreads();

    // Phase B: wave wv owns col-tiles 2wv, 2wv+1.
    int quad = lane >> 4;
    int lcol = lane & 15;

    f32x4 acc[2];
    acc[0] = (f32x4)0.0f;
    acc[1] = (f32x4)0.0f;

    #pragma unroll
    for (int kk = 0; kk < 4; ++kk) {
        int kof = kk * 32 + quad * 8;
        bf16x8 av = *(const bf16x8*)&xs[lcol][kof];
        #pragma unroll
        for (int p = 0; p < 2; ++p) {
            int tt = wv * 2 + p;
            bf16x8 bf = *(const bf16x8*)(Bt + (size_t)(tt * 16 + lcol) * 256 + kof);
            acc[p] = __builtin_amdgcn_mfma_f32_16x16x32_bf16(av, bf, acc[p], 0, 0, 0);
        }
    }
    #pragma unroll
    for (int kk = 0; kk < 4; ++kk) {
        int kof = kk * 32 + quad * 8;
        bf16x8 av = *(const bf16x8*)&as[lcol][kof];
        #pragma unroll
        for (int p = 0; p < 2; ++p) {
            int tt = wv * 2 + p;
            bf16x8 bf = *(const bf16x8*)(Bt + (size_t)(tt * 16 + lcol) * 256 + 128 + kof);
            acc[p] = __builtin_amdgcn_mfma_f32_16x16x32_bf16(av, bf, acc[p], 0, 0, 0);
        }
    }

    // bias + ReLU; per-wave 32-col LN partials
    float h[2][4];
    float s[4] = {0, 0, 0, 0}, q[4] = {0, 0, 0, 0};
    float gam[2], bet[2];
    #pragma unroll
    for (int p = 0; p < 2; ++p) {
        int col = (wv * 2 + p) * 16 + lcol;
        float bs = bself[col] + bnb[col];
        gam[p] = gamma[col];
        bet[p] = beta[col];
        #pragma unroll
        for (int r = 0; r < 4; ++r) {
            float v = fmaxf(acc[p][r] + bs, 0.0f);
            h[p][r] = v;
            s[r] += v;
            q[r] += v * v;
        }
    }
    #pragma unroll
    for (int r = 0; r < 4; ++r) {
        #pragma unroll
        for (int off = 1; off <= 8; off <<= 1) {
            s[r] += __shfl_xor(s[r], off, 64);
            q[r] += __shfl_xor(q[r], off, 64);
        }
    }
    if (lcol == 0) {
        #pragma unroll
        for (int r = 0; r < 4; ++r) {
            red[wv][0][quad * 4 + r] = s[r];
            red[wv][1][quad * 4 + r] = q[r];
        }
    }
    __syncthreads();

    #pragma unroll
    for (int r = 0; r < 4; ++r) {
        int row = quad * 4 + r;
        int irow = i0 + row;
        if (irow >= N_) continue;
        float S = red[0][0][row] + red[1][0][row] + red[2][0][row] + red[3][0][row];
        float Q = red[0][1][row] + red[1][1][row] + red[2][1][row] + red[3][1][row];
        float mu = S * (1.0f / D_);
        float var = Q * (1.0f / D_) - mu * mu;
        float rin = rsqrtf(fmaxf(var, 0.0f) + EPS_);
        int g = b * N_ + irow;
        float mk = nmask[g];
        float* op = out + (size_t)g * D_;
        #pragma unroll
        for (int p = 0; p < 2; ++p) {
            int col = (wv * 2 + p) * 16 + lcol;
            op[col] = ((h[p][r] - mu) * rin * gam[p] + bet[p]) * mk;
        }
    }
}

extern "C" void kernel_launch(void* const* d_in, const int* in_sizes, int n_in,
                              void* d_out, int out_size, void* d_ws, size_t ws_size,
                              hipStream_t stream)
{
    const float* x     = (const float*)d_in[0];
    const int*   ei    = (const int*)d_in[1];
    const float* nmask = (const float*)d_in[2];
    const float* em    = (const float*)d_in[3];
    const float* Wself = (const float*)d_in[4];
    const float* bself = (const float*)d_in[5];
    const float* Wnb   = (const float*)d_in[6];
    const float* bnb   = (const float*)d_in[7];
    const float* gamma = (const float*)d_in[8];
    const float* beta  = (const float*)d_in[9];
    float* out = (float*)d_out;

    // ws: cnt int[40000] | entries u32[40000*64] (10.24 MB) | Bt bf16[128*256]
    //     | xbf bf16[40000*128] (10.24 MB)   -> ~21 MB total
    int* cnt = (int*)d_ws;
    unsigned int* entries = (unsigned int*)(cnt + NNODES);
    unsigned short* Bt = (unsigned short*)(entries + (size_t)NNODES * CAP);
    unsigned short* xbf = Bt + (size_t)128 * 256;                // 16-aligned

    hipMemsetAsync(cnt, 0, NNODES * sizeof(int), stream);
    fill_k<<<FILL_BLOCKS + CONV_BLOCKS + 128, 256, 0, stream>>>(
        ei, em, cnt, entries, x, xbf, Wself, Wnb, Bt);
    fused_k<<<8 * JB, 256, 0, stream>>>(xbf, cnt, entries, Bt,
                                        bself, bnb, gamma, beta, nmask, out);
}

// Round 7
// 174.762 us; speedup vs baseline: 1.0617x; 1.0617x over previous
//
#include <hip/hip_runtime.h>

// GraphSAGE layer: B=8, N=5000, E=100000, D=128. All float tensors f32; edge_index int32.
// R24 (3 dispatches, R18 shell): memset(cnt) -> fill (1 edge/thread + x->bf16 + packW)
//   -> fused (group-parallel gather FROM F32 X + f32x4 vector accum -> MFMA + LN).
// R23 post-mortem: DMA gather 67us @ 20% occ -> falsified; reverted. Accounting:
// fixed ~75 + fill ~42 + fused ~44. R24 levers: (a) fused gathers from f32 x (kills
// the 8 bf16-unpack VALU/slot; f32x4 FMA can emit v_pk_fma_f32) -> tests VALU-issue
// bound; (b) fill 1 edge/thread (halves the chained atomic->store L2 latency per
// thread) -> tests chain-latency vs atomic-channel-throughput for fill.

#define B_ 8
#define N_ 5000
#define E_ 100000
#define D_ 128
#define EPS_ 1e-5f
#define NNODES (B_ * N_)   // 40000
#define JB 313             // 16-node blocks per batch (312*16+8 = 5000)
#define EPB ((E_ + 255) / 256)        // 391 edge-blocks per batch (1 edge/thread)
#define FILL_BLOCKS (8 * EPB)         // 3128
#define CONV_BLOCKS 2500              // x -> bf16: 2048 elems/block
#define CAP 64             // bucket capacity per node (avg deg 20, P(ovf) ~ 5e-14)
#define LDSP 136           // padded bf16 row stride (272 B -> 2-way bank alias, free)

typedef __bf16 bf16x8 __attribute__((ext_vector_type(8)));
typedef float  f32x4  __attribute__((ext_vector_type(4)));

static __device__ __forceinline__ unsigned short f2bf(float f) {
    union { float f; unsigned int i; } c; c.f = f;
    unsigned int i = c.i;
    i += 0x7fffu + ((i >> 16) & 1u);
    return (unsigned short)(i >> 16);
}

// ---------- fill: XCD-affine u32 buckets (1 edge/thread) + x->bf16 + packW ----------
__global__ __launch_bounds__(256) void fill_k(
    const int* __restrict__ ei, const float* __restrict__ em,
    int* __restrict__ cnt, unsigned int* __restrict__ entries,
    const float* __restrict__ x, unsigned short* __restrict__ xbf,
    const float* __restrict__ Wself, const float* __restrict__ Wnb,
    unsigned short* __restrict__ Bt)
{
    int blk = blockIdx.x;
    if (blk < FILL_BLOCKS) {
        int b = blk & 7;                    // batch -> XCD (round-robin dispatch)
        int e = (blk >> 3) * 256 + threadIdx.x;
        if (e >= E_) return;
        const int* eib = ei + (size_t)b * 2 * E_;
        int   sv = eib[e];
        int   tv = eib[E_ + e];
        float mv = em[(size_t)b * E_ + e];
        int gb = b * N_;
        int g = gb + tv;
        int ok = (mv != 0.0f);
        int slot = atomicAdd(&cnt[g], ok);  // one atomic + one dependent store/thread
        if (ok && slot < CAP)
            entries[((size_t)g << 6) + slot] =
                (unsigned int)(gb + sv) | ((unsigned int)f2bf(mv) << 16);
    } else if (blk < FILL_BLOCKS + CONV_BLOCKS) {
        size_t base = (size_t)(blk - FILL_BLOCKS) * 2048 + threadIdx.x * 8;
        float4 va = *(const float4*)(x + base);
        float4 vb = *(const float4*)(x + base + 4);
        uint4 o;
        o.x = (unsigned int)f2bf(va.x) | ((unsigned int)f2bf(va.y) << 16);
        o.y = (unsigned int)f2bf(va.z) | ((unsigned int)f2bf(va.w) << 16);
        o.z = (unsigned int)f2bf(vb.x) | ((unsigned int)f2bf(vb.y) << 16);
        o.w = (unsigned int)f2bf(vb.z) | ((unsigned int)f2bf(vb.w) << 16);
        *(uint4*)(xbf + base) = o;
    } else {
        int n = blk - FILL_BLOCKS - CONV_BLOCKS;   // 0..127
        int k = threadIdx.x;                       // 0..255
        float v = (k < 128) ? Wself[(size_t)k * D_ + n]
                            : Wnb[(size_t)(k - 128) * D_ + n];
        Bt[(size_t)n * 256 + k] = f2bf(v);
    }
}

// ---------- fused: f32 gather + MFMA GEMM + ReLU + LN + mask (R18 structure) ----------
// Grid 8*JB; blk&7 = batch (XCD affinity), blk>>3 = 16-node group within batch.
__global__ __launch_bounds__(256) void fused_k(
    const float* __restrict__ x, const unsigned short* __restrict__ xbf,
    const int* __restrict__ cnt, const unsigned int* __restrict__ entries,
    const unsigned short* __restrict__ Bt,
    const float* __restrict__ bself, const float* __restrict__ bnb,
    const float* __restrict__ gamma, const float* __restrict__ beta,
    const float* __restrict__ nmask, float* __restrict__ out)
{
    __shared__ unsigned short xs[16][LDSP];
    __shared__ unsigned short as[16][LDSP];
    __shared__ float red[4][2][16];

    int t = threadIdx.x;
    int lane = t & 63, wv = t >> 6;
    int b = blockIdx.x & 7;
    int j = blockIdx.x >> 3;               // 0..JB-1
    int i0 = j * 16;
    int g0 = b * N_ + i0;
    int limit = N_ - i0; if (limit > 16) limit = 16;

    int grp = lane >> 4;                   // lane-group: which of the wave's 4 nodes
    int c8  = lane & 15;                   // 32B chunk (8 f32) within the 512B row
    int myrow = (wv << 2) + grp;           // 0..15: node row owned by this lane-group

    // Issue gather metadata loads first; latency hides under xs staging.
    int ga = g0 + ((myrow < limit) ? myrow : 0);      // clamped (valid addr)
    int dgr = cnt[ga];
    const unsigned int* ep = entries + ((size_t)ga << 6);
    unsigned int ee = ep[c8];              // slots 0..15, lane c8 holds slot c8

    // Phase A1: stage own xbf rows into LDS (4 rows/wave).
    #pragma unroll
    for (int lr = wv * 4; lr < wv * 4 + 4; ++lr) {
        unsigned int v = 0;
        if (lr < limit)
            v = ((const unsigned int*)(xbf + (size_t)(g0 + lr) * D_))[lane];
        ((unsigned int*)&xs[lr][0])[lane] = v;
    }

    // Phase A2: group-parallel gather from f32 x. Lane (grp,c8) owns elements
    // 8*c8..8*c8+7 of its node's masked neighbor sum; f32x4 accum (v_pk_fma_f32).
    int dgg = (myrow < limit) ? ((dgr > CAP) ? CAP : dgr) : 0;

    f32x4 a0 = (f32x4)0.0f, a1 = (f32x4)0.0f;
    float cs = 0.f;

    for (int k0 = 0; ; k0 += 16) {
        unsigned int een = 0u;
        if (k0 + 16 < CAP)                  // prefetch next slot chunk
            een = ep[(k0 + 16) + c8];
        #pragma unroll 8
        for (int k = 0; k < 16; ++k) {
            unsigned int ej = (unsigned int)__shfl((int)ee, (lane & 48) + k, 64);
            int   ok = (k0 + k) < dgg;
            int   sj = ok ? (int)(ej & 0xffffu) : 0;              // masked -> row 0
            float mj = ok ? __uint_as_float(ej & 0xffff0000u) : 0.0f;
            const float* xp = x + ((size_t)sj << 7) + (c8 << 3);
            f32x4 vlo = *(const f32x4*)xp;
            f32x4 vhi = *(const f32x4*)(xp + 4);
            a0 += vlo * mj;
            a1 += vhi * mj;
            cs += mj;
        }
        if (k0 + 16 >= CAP) break;
        if (__all(dgg <= k0 + 16)) break;   // all 4 nodes of this wave done
        ee = een;
    }

    // cs is uniform within the group (every lane summed every edge's m).
    {
        float inv = 1.0f / fmaxf(cs, 1.0f);
        uint4 o;
        o.x = (unsigned int)f2bf(a0[0] * inv) | ((unsigned int)f2bf(a0[1] * inv) << 16);
        o.y = (unsigned int)f2bf(a0[2] * inv) | ((unsigned int)f2bf(a0[3] * inv) << 16);
        o.z = (unsigned int)f2bf(a1[0] * inv) | ((unsigned int)f2bf(a1[1] * inv) << 16);
        o.w = (unsigned int)f2bf(a1[2] * inv) | ((unsigned int)f2bf(a1[3] * inv) << 16);
        *(uint4*)&as[myrow][c8 << 3] = o;   // rows >= limit: dgg=0 -> zeros
    }
    __syncthreads();

    // Phase B: wave wv owns col-tiles 2wv, 2wv+1.
    int quad = lane >> 4;
    int lcol = lane & 15;

    f32x4 acc[2];
    acc[0] = (f32x4)0.0f;
    acc[1] = (f32x4)0.0f;

    #pragma unroll
    for (int kk = 0; kk < 4; ++kk) {
        int kof = kk * 32 + quad * 8;
        bf16x8 av = *(const bf16x8*)&xs[lcol][kof];
        #pragma unroll
        for (int p = 0; p < 2; ++p) {
            int tt = wv * 2 + p;
            bf16x8 bf = *(const bf16x8*)(Bt + (size_t)(tt * 16 + lcol) * 256 + kof);
            acc[p] = __builtin_amdgcn_mfma_f32_16x16x32_bf16(av, bf, acc[p], 0, 0, 0);
        }
    }
    #pragma unroll
    for (int kk = 0; kk < 4; ++kk) {
        int kof = kk * 32 + quad * 8;
        bf16x8 av = *(const bf16x8*)&as[lcol][kof];
        #pragma unroll
        for (int p = 0; p < 2; ++p) {
            int tt = wv * 2 + p;
            bf16x8 bf = *(const bf16x8*)(Bt + (size_t)(tt * 16 + lcol) * 256 + 128 + kof);
            acc[p] = __builtin_amdgcn_mfma_f32_16x16x32_bf16(av, bf, acc[p], 0, 0, 0);
        }
    }

    // bias + ReLU; per-wave 32-col LN partials
    float h[2][4];
    float s[4] = {0, 0, 0, 0}, q[4] = {0, 0, 0, 0};
    float gam[2], bet[2];
    #pragma unroll
    for (int p = 0; p < 2; ++p) {
        int col = (wv * 2 + p) * 16 + lcol;
        float bs = bself[col] + bnb[col];
        gam[p] = gamma[col];
        bet[p] = beta[col];
        #pragma unroll
        for (int r = 0; r < 4; ++r) {
            float v = fmaxf(acc[p][r] + bs, 0.0f);
            h[p][r] = v;
            s[r] += v;
            q[r] += v * v;
        }
    }
    #pragma unroll
    for (int r = 0; r < 4; ++r) {
        #pragma unroll
        for (int off = 1; off <= 8; off <<= 1) {
            s[r] += __shfl_xor(s[r], off, 64);
            q[r] += __shfl_xor(q[r], off, 64);
        }
    }
    if (lcol == 0) {
        #pragma unroll
        for (int r = 0; r < 4; ++r) {
            red[wv][0][quad * 4 + r] = s[r];
            red[wv][1][quad * 4 + r] = q[r];
        }
    }
    __syncthreads();

    #pragma unroll
    for (int r = 0; r < 4; ++r) {
        int row = quad * 4 + r;
        int irow = i0 + row;
        if (irow >= N_) continue;
        float S = red[0][0][row] + red[1][0][row] + red[2][0][row] + red[3][0][row];
        float Q = red[0][1][row] + red[1][1][row] + red[2][1][row] + red[3][1][row];
        float mu = S * (1.0f / D_);
        float var = Q * (1.0f / D_) - mu * mu;
        float rin = rsqrtf(fmaxf(var, 0.0f) + EPS_);
        int g = b * N_ + irow;
        float mk = nmask[g];
        float* op = out + (size_t)g * D_;
        #pragma unroll
        for (int p = 0; p < 2; ++p) {
            int col = (wv * 2 + p) * 16 + lcol;
            op[col] = ((h[p][r] - mu) * rin * gam[p] + bet[p]) * mk;
        }
    }
}

extern "C" void kernel_launch(void* const* d_in, const int* in_sizes, int n_in,
                              void* d_out, int out_size, void* d_ws, size_t ws_size,
                              hipStream_t stream)
{
    const float* x     = (const float*)d_in[0];
    const int*   ei    = (const int*)d_in[1];
    const float* nmask = (const float*)d_in[2];
    const float* em    = (const float*)d_in[3];
    const float* Wself = (const float*)d_in[4];
    const float* bself = (const float*)d_in[5];
    const float* Wnb   = (const float*)d_in[6];
    const float* bnb   = (const float*)d_in[7];
    const float* gamma = (const float*)d_in[8];
    const float* beta  = (const float*)d_in[9];
    float* out = (float*)d_out;

    // ws: cnt int[40000] | entries u32[40000*64] (10.24 MB) | Bt bf16[128*256]
    //     | xbf bf16[40000*128] (10.24 MB)   -> ~21 MB total
    int* cnt = (int*)d_ws;
    unsigned int* entries = (unsigned int*)(cnt + NNODES);
    unsigned short* Bt = (unsigned short*)(entries + (size_t)NNODES * CAP);
    unsigned short* xbf = Bt + (size_t)128 * 256;                // 16-aligned

    hipMemsetAsync(cnt, 0, NNODES * sizeof(int), stream);
    fill_k<<<FILL_BLOCKS + CONV_BLOCKS + 128, 256, 0, stream>>>(
        ei, em, cnt, entries, x, xbf, Wself, Wnb, Bt);
    fused_k<<<8 * JB, 256, 0, stream>>>(x, xbf, cnt, entries, Bt,
                                        bself, bnb, gamma, beta, nmask, out);
}

// Round 8
// 161.478 us; speedup vs baseline: 1.1491x; 1.0823x over previous
//
#include <hip/hip_runtime.h>

// GraphSAGE layer: B=8, N=5000, E=100000, D=128. All float tensors f32; edge_index int32.
// R25 (3 dispatches, R18 shell): memset(cnt) -> fill (R18's 2-edge pairs + x->bf16 +
//   packW) -> fused (group-parallel bf16 gather with HOISTED bpermute batches).
// R24 post-mortem: f32 gather 56us (VALU down, segments up => segment-bound, VALU
// excluded); fill 1-edge/thread null (throughput-bound). Reverted both.
// R25 single variable: all per-slot __shfl (ds_bpermute, LGKM pipe) are hoisted out
// of the scattered-load loop into one 16-wide batch per 16 slots (1 lgkm sync each),
// so the load+FMA chunks contain zero LDS ops and scattered loads pipeline clean.
// Segment count byte-identical to R18. Null here => ILP/TLP/VALU/segments/DMA/LGKM
// all individually excluded -> scattered-segment wall is the hardware floor.

#define B_ 8
#define N_ 5000
#define E_ 100000
#define D_ 128
#define EPS_ 1e-5f
#define NNODES (B_ * N_)   // 40000
#define JB 313             // 16-node blocks per batch (312*16+8 = 5000)
#define PPB ((E_ / 2 + 255) / 256)    // 196 pair-blocks per batch (E even)
#define FILL_BLOCKS (8 * PPB)         // 1568
#define CONV_BLOCKS 2500              // x -> bf16: 2048 elems/block
#define CAP 64             // bucket capacity per node (avg deg 20, P(ovf) ~ 5e-14)
#define LDSP 136           // padded bf16 row stride (272 B -> 2-way bank alias, free)

typedef __bf16 bf16x8 __attribute__((ext_vector_type(8)));
typedef float  f32x4  __attribute__((ext_vector_type(4)));

static __device__ __forceinline__ unsigned short f2bf(float f) {
    union { float f; unsigned int i; } c; c.f = f;
    unsigned int i = c.i;
    i += 0x7fffu + ((i >> 16) & 1u);
    return (unsigned short)(i >> 16);
}
static __device__ __forceinline__ float bflo(unsigned int u) {
    return __uint_as_float(u << 16);
}
static __device__ __forceinline__ float bfhi(unsigned int u) {
    return __uint_as_float(u & 0xffff0000u);
}

// ---------- fill: XCD-affine u32 buckets (0..1567) + x->bf16 (..4067) + packW ----------
__global__ __launch_bounds__(256) void fill_k(
    const int* __restrict__ ei, const float* __restrict__ em,
    int* __restrict__ cnt, unsigned int* __restrict__ entries,
    const float* __restrict__ x, unsigned short* __restrict__ xbf,
    const float* __restrict__ Wself, const float* __restrict__ Wnb,
    unsigned short* __restrict__ Bt)
{
    int blk = blockIdx.x;
    if (blk < FILL_BLOCKS) {
        int b = blk & 7;                    // batch -> XCD (round-robin dispatch)
        int p = (blk >> 3) * 256 + threadIdx.x;
        if (p >= E_ / 2) return;
        int e = 2 * p;                      // pair e, e+1 (E even -> both valid)
        const int* eib = ei + (size_t)b * 2 * E_;
        int2   sv = *(const int2*)(eib + e);
        int2   tv = *(const int2*)(eib + E_ + e);
        float2 mv = *(const float2*)(em + (size_t)b * E_ + e);
        int gb = b * N_;
        int g0 = gb + tv.x, g1 = gb + tv.y;
        int e0 = (mv.x != 0.0f), e1 = (mv.y != 0.0f);
        // Issue both atomics before either dependent store (overlap L2 round trips).
        int s0 = atomicAdd(&cnt[g0], e0);
        int s1 = atomicAdd(&cnt[g1], e1);
        if (e0 && s0 < CAP)
            entries[((size_t)g0 << 6) + s0] =
                (unsigned int)(gb + sv.x) | ((unsigned int)f2bf(mv.x) << 16);
        if (e1 && s1 < CAP)
            entries[((size_t)g1 << 6) + s1] =
                (unsigned int)(gb + sv.y) | ((unsigned int)f2bf(mv.y) << 16);
    } else if (blk < FILL_BLOCKS + CONV_BLOCKS) {
        size_t base = (size_t)(blk - FILL_BLOCKS) * 2048 + threadIdx.x * 8;
        float4 va = *(const float4*)(x + base);
        float4 vb = *(const float4*)(x + base + 4);
        uint4 o;
        o.x = (unsigned int)f2bf(va.x) | ((unsigned int)f2bf(va.y) << 16);
        o.y = (unsigned int)f2bf(va.z) | ((unsigned int)f2bf(va.w) << 16);
        o.z = (unsigned int)f2bf(vb.x) | ((unsigned int)f2bf(vb.y) << 16);
        o.w = (unsigned int)f2bf(vb.z) | ((unsigned int)f2bf(vb.w) << 16);
        *(uint4*)(xbf + base) = o;
    } else {
        int n = blk - FILL_BLOCKS - CONV_BLOCKS;   // 0..127
        int k = threadIdx.x;                       // 0..255
        float v = (k < 128) ? Wself[(size_t)k * D_ + n]
                            : Wnb[(size_t)(k - 128) * D_ + n];
        Bt[(size_t)n * 256 + k] = f2bf(v);
    }
}

// 8-slot load+FMA chunk: NO LDS ops inside. EJ = ej array, KO = index offset into
// EJ, SB = absolute slot base for masking. Masked slots -> hot row 0, m=0.
#define GC8(EJ, KO, SB)                                                       \
  {                                                                           \
    uint4 v[8]; float mj[8];                                                  \
    _Pragma("unroll")                                                         \
    for (int k = 0; k < 8; ++k) {                                             \
      int ok = (SB) + k < dgg;                                                \
      int sj = ok ? (int)(EJ[(KO) + k] & 0xffffu) : 0;                        \
      mj[k] = ok ? __uint_as_float(EJ[(KO) + k] & 0xffff0000u) : 0.0f;        \
      v[k] = *(const uint4*)(xbf + ((size_t)sj << 7) + (c8 << 3));            \
    }                                                                         \
    _Pragma("unroll")                                                         \
    for (int k = 0; k < 8; ++k) {                                             \
      float m = mj[k];                                                        \
      a[0] += bflo(v[k].x) * m; a[1] += bfhi(v[k].x) * m;                     \
      a[2] += bflo(v[k].y) * m; a[3] += bfhi(v[k].y) * m;                     \
      a[4] += bflo(v[k].z) * m; a[5] += bfhi(v[k].z) * m;                     \
      a[6] += bflo(v[k].w) * m; a[7] += bfhi(v[k].w) * m;                     \
      cs += m;                                                                \
    }                                                                         \
  }

// ---------- fused: hoisted-shfl gather + MFMA GEMM + ReLU + LN + mask ----------
// Grid 8*JB; blk&7 = batch (XCD affinity), blk>>3 = 16-node group within batch.
__global__ __launch_bounds__(256) void fused_k(
    const unsigned short* __restrict__ xbf, const int* __restrict__ cnt,
    const unsigned int* __restrict__ entries,
    const unsigned short* __restrict__ Bt,
    const float* __restrict__ bself, const float* __restrict__ bnb,
    const float* __restrict__ gamma, const float* __restrict__ beta,
    const float* __restrict__ nmask, float* __restrict__ out)
{
    __shared__ unsigned short xs[16][LDSP];
    __shared__ unsigned short as[16][LDSP];
    __shared__ float red[4][2][16];

    int t = threadIdx.x;
    int lane = t & 63, wv = t >> 6;
    int b = blockIdx.x & 7;
    int j = blockIdx.x >> 3;               // 0..JB-1
    int i0 = j * 16;
    int g0 = b * N_ + i0;
    int limit = N_ - i0; if (limit > 16) limit = 16;

    int grp = lane >> 4;                   // lane-group: which of the wave's 4 nodes
    int c8  = lane & 15;                   // 16B chunk (8 bf16) within the 256B row
    int lanebase = lane & 48;
    int myrow = (wv << 2) + grp;           // 0..15: node row owned by this lane-group

    // Issue gather metadata loads first; latency hides under xs staging.
    int ga = g0 + ((myrow < limit) ? myrow : 0);      // clamped (valid addr)
    int dgr = cnt[ga];
    const unsigned int* ep = entries + ((size_t)ga << 6);
    unsigned int ee0 = ep[c8];             // slots 0..15 (lane c8 holds slot c8)
    unsigned int ee1 = ep[16 + c8];        // slots 16..31 (deg>16 w.p. 0.78)

    // Phase A1: stage own xbf rows into LDS (4 rows/wave).
    #pragma unroll
    for (int lr = wv * 4; lr < wv * 4 + 4; ++lr) {
        unsigned int v = 0;
        if (lr < limit)
            v = ((const unsigned int*)(xbf + (size_t)(g0 + lr) * D_))[lane];
        ((unsigned int*)&xs[lr][0])[lane] = v;
    }

    // Phase A2: group-parallel gather, bpermutes hoisted in 16-wide batches.
    int dgg = (myrow < limit) ? ((dgr > CAP) ? CAP : dgr) : 0;

    float a[8];
    #pragma unroll
    for (int i = 0; i < 8; ++i) a[i] = 0.f;
    float cs = 0.f;

    // Batch A: all 16 bpermutes for slots 0..15 up front (single lgkm sync),
    // then pure load+FMA chunks with zero LDS ops.
    unsigned int ej[16];
    #pragma unroll
    for (int k = 0; k < 16; ++k)
        ej[k] = (unsigned int)__shfl((int)ee0, lanebase + k, 64);

    if (0 < dgg) GC8(ej, 0, 0);
    if (8 < dgg) GC8(ej, 8, 8);

    if (__any(dgg > 16)) {                 // batch B: slots 16..31
        #pragma unroll
        for (int k = 0; k < 16; ++k)
            ej[k] = (unsigned int)__shfl((int)ee1, lanebase + k, 64);
        if (16 < dgg) GC8(ej, 0, 16);
        if (24 < dgg) GC8(ej, 8, 24);
    }

    if (__any(dgg > 32)) {                 // rare tail (P ~ 0.4% of waves)
        #pragma unroll 1
        for (int k0 = 32; k0 < CAP; k0 += 8) {
            if (__all(dgg <= k0)) break;
            unsigned int ejt[8];
            #pragma unroll
            for (int kk = 0; kk < 8; ++kk)
                ejt[kk] = ep[k0 + kk];     // group-uniform addr -> broadcast
            if (k0 < dgg) GC8(ejt, 0, k0);
        }
    }

    // cs is uniform within the group (every lane summed every edge's m).
    {
        float inv = 1.0f / fmaxf(cs, 1.0f);
        uint4 o;
        o.x = (unsigned int)f2bf(a[0] * inv) | ((unsigned int)f2bf(a[1] * inv) << 16);
        o.y = (unsigned int)f2bf(a[2] * inv) | ((unsigned int)f2bf(a[3] * inv) << 16);
        o.z = (unsigned int)f2bf(a[4] * inv) | ((unsigned int)f2bf(a[5] * inv) << 16);
        o.w = (unsigned int)f2bf(a[6] * inv) | ((unsigned int)f2bf(a[7] * inv) << 16);
        *(uint4*)&as[myrow][c8 << 3] = o;   // rows >= limit: dgg=0 -> zeros
    }
    __syncthreads();

    // Phase B: wave wv owns col-tiles 2wv, 2wv+1.
    int quad = lane >> 4;
    int lcol = lane & 15;

    f32x4 acc[2];
    acc[0] = (f32x4)0.0f;
    acc[1] = (f32x4)0.0f;

    #pragma unroll
    for (int kk = 0; kk < 4; ++kk) {
        int kof = kk * 32 + quad * 8;
        bf16x8 av = *(const bf16x8*)&xs[lcol][kof];
        #pragma unroll
        for (int p = 0; p < 2; ++p) {
            int tt = wv * 2 + p;
            bf16x8 bf = *(const bf16x8*)(Bt + (size_t)(tt * 16 + lcol) * 256 + kof);
            acc[p] = __builtin_amdgcn_mfma_f32_16x16x32_bf16(av, bf, acc[p], 0, 0, 0);
        }
    }
    #pragma unroll
    for (int kk = 0; kk < 4; ++kk) {
        int kof = kk * 32 + quad * 8;
        bf16x8 av = *(const bf16x8*)&as[lcol][kof];
        #pragma unroll
        for (int p = 0; p < 2; ++p) {
            int tt = wv * 2 + p;
            bf16x8 bf = *(const bf16x8*)(Bt + (size_t)(tt * 16 + lcol) * 256 + 128 + kof);
            acc[p] = __builtin_amdgcn_mfma_f32_16x16x32_bf16(av, bf, acc[p], 0, 0, 0);
        }
    }

    // bias + ReLU; per-wave 32-col LN partials
    float h[2][4];
    float s[4] = {0, 0, 0, 0}, q[4] = {0, 0, 0, 0};
    float gam[2], bet[2];
    #pragma unroll
    for (int p = 0; p < 2; ++p) {
        int col = (wv * 2 + p) * 16 + lcol;
        float bs = bself[col] + bnb[col];
        gam[p] = gamma[col];
        bet[p] = beta[col];
        #pragma unroll
        for (int r = 0; r < 4; ++r) {
            float v = fmaxf(acc[p][r] + bs, 0.0f);
            h[p][r] = v;
            s[r] += v;
            q[r] += v * v;
        }
    }
    #pragma unroll
    for (int r = 0; r < 4; ++r) {
        #pragma unroll
        for (int off = 1; off <= 8; off <<= 1) {
            s[r] += __shfl_xor(s[r], off, 64);
            q[r] += __shfl_xor(q[r], off, 64);
        }
    }
    if (lcol == 0) {
        #pragma unroll
        for (int r = 0; r < 4; ++r) {
            red[wv][0][quad * 4 + r] = s[r];
            red[wv][1][quad * 4 + r] = q[r];
        }
    }
    __syncthreads();

    #pragma unroll
    for (int r = 0; r < 4; ++r) {
        int row = quad * 4 + r;
        int irow = i0 + row;
        if (irow >= N_) continue;
        float S = red[0][0][row] + red[1][0][row] + red[2][0][row] + red[3][0][row];
        float Q = red[0][1][row] + red[1][1][row] + red[2][1][row] + red[3][1][row];
        float mu = S * (1.0f / D_);
        float var = Q * (1.0f / D_) - mu * mu;
        float rin = rsqrtf(fmaxf(var, 0.0f) + EPS_);
        int g = b * N_ + irow;
        float mk = nmask[g];
        float* op = out + (size_t)g * D_;
        #pragma unroll
        for (int p = 0; p < 2; ++p) {
            int col = (wv * 2 + p) * 16 + lcol;
            op[col] = ((h[p][r] - mu) * rin * gam[p] + bet[p]) * mk;
        }
    }
}

extern "C" void kernel_launch(void* const* d_in, const int* in_sizes, int n_in,
                              void* d_out, int out_size, void* d_ws, size_t ws_size,
                              hipStream_t stream)
{
    const float* x     = (const float*)d_in[0];
    const int*   ei    = (const int*)d_in[1];
    const float* nmask = (const float*)d_in[2];
    const float* em    = (const float*)d_in[3];
    const float* Wself = (const float*)d_in[4];
    const float* bself = (const float*)d_in[5];
    const float* Wnb   = (const float*)d_in[6];
    const float* bnb   = (const float*)d_in[7];
    const float* gamma = (const float*)d_in[8];
    const float* beta  = (const float*)d_in[9];
    float* out = (float*)d_out;

    // ws: cnt int[40000] | entries u32[40000*64] (10.24 MB) | Bt bf16[128*256]
    //     | xbf bf16[40000*128] (10.24 MB)   -> ~21 MB total
    int* cnt = (int*)d_ws;
    unsigned int* entries = (unsigned int*)(cnt + NNODES);
    unsigned short* Bt = (unsigned short*)(entries + (size_t)NNODES * CAP);
    unsigned short* xbf = Bt + (size_t)128 * 256;                // 16-aligned

    hipMemsetAsync(cnt, 0, NNODES * sizeof(int), stream);
    fill_k<<<FILL_BLOCKS + CONV_BLOCKS + 128, 256, 0, stream>>>(
        ei, em, cnt, entries, x, xbf, Wself, Wnb, Bt);
    fused_k<<<8 * JB, 256, 0, stream>>>(xbf, cnt, entries, Bt,
                                        bself, bnb, gamma, beta, nmask, out);
}

// Round 10
// 160.888 us; speedup vs baseline: 1.1533x; 1.0037x over previous
//
#include <hip/hip_runtime.h>
#include <hip/hip_fp16.h>

// GraphSAGE layer: B=8, N=5000, E=100000, D=128. All float tensors f32; edge_index int32.
// R26b (resubmit of R26 after infra-level "container failed twice"; no kernel verdict
// was obtained). 3 dispatches, R25 shell: memset(cnt) -> fill (2-edge pairs + x->F16
// + packW F16) -> fused (hoisted-bpermute gather, PACKED __hfma2 accum, MFMA _f16, LN).
// Theory under test: fused's ~33us intercept (R18<->R24 segment-count fit: slope
// ~2.2cy/seg = 12us, intercept 33us) is VALU issue volume. bf16->f16 halves per-slot
// VALU (8 unpack + 8 scalar FMA -> 4 v_pk_fma_f16) at identical segments/bytes.
// Null => VALU excluded -> scattered-load wall is structural.

#define B_ 8
#define N_ 5000
#define E_ 100000
#define D_ 128
#define EPS_ 1e-5f
#define NNODES (B_ * N_)   // 40000
#define JB 313             // 16-node blocks per batch (312*16+8 = 5000)
#define PPB ((E_ / 2 + 255) / 256)    // 196 pair-blocks per batch (E even)
#define FILL_BLOCKS (8 * PPB)         // 1568
#define CONV_BLOCKS 2500              // x -> f16: 2048 elems/block
#define CAP 64             // bucket capacity per node (avg deg 20, P(ovf) ~ 5e-14)
#define LDSP 136           // padded f16 row stride (272 B -> 2-way bank alias, free)

typedef _Float16 f16x8 __attribute__((ext_vector_type(8)));
typedef float    f32x4 __attribute__((ext_vector_type(4)));

static __device__ __forceinline__ unsigned short f2h(float f) {
    _Float16 h = (_Float16)f;
    union { _Float16 h; unsigned short u; } c; c.h = h;
    return c.u;
}
static __device__ __forceinline__ float h2f(unsigned short u) {
    union { _Float16 h; unsigned short u; } c; c.u = u;
    return (float)c.h;
}

// ---------- fill: XCD-affine u32 buckets {src:16|f16(m):16} + x->f16 + packW ----------
__global__ __launch_bounds__(256) void fill_k(
    const int* __restrict__ ei, const float* __restrict__ em,
    int* __restrict__ cnt, unsigned int* __restrict__ entries,
    const float* __restrict__ x, unsigned short* __restrict__ xh,
    const float* __restrict__ Wself, const float* __restrict__ Wnb,
    unsigned short* __restrict__ Bt)
{
    int blk = blockIdx.x;
    if (blk < FILL_BLOCKS) {
        int b = blk & 7;                    // batch -> XCD (round-robin dispatch)
        int p = (blk >> 3) * 256 + threadIdx.x;
        if (p >= E_ / 2) return;
        int e = 2 * p;                      // pair e, e+1 (E even -> both valid)
        const int* eib = ei + (size_t)b * 2 * E_;
        int2   sv = *(const int2*)(eib + e);
        int2   tv = *(const int2*)(eib + E_ + e);
        float2 mv = *(const float2*)(em + (size_t)b * E_ + e);
        int gb = b * N_;
        int g0 = gb + tv.x, g1 = gb + tv.y;
        int e0 = (mv.x != 0.0f), e1 = (mv.y != 0.0f);
        // Issue both atomics before either dependent store (overlap L2 round trips).
        int s0 = atomicAdd(&cnt[g0], e0);
        int s1 = atomicAdd(&cnt[g1], e1);
        if (e0 && s0 < CAP)
            entries[((size_t)g0 << 6) + s0] =
                (unsigned int)(gb + sv.x) | ((unsigned int)f2h(mv.x) << 16);
        if (e1 && s1 < CAP)
            entries[((size_t)g1 << 6) + s1] =
                (unsigned int)(gb + sv.y) | ((unsigned int)f2h(mv.y) << 16);
    } else if (blk < FILL_BLOCKS + CONV_BLOCKS) {
        size_t base = (size_t)(blk - FILL_BLOCKS) * 2048 + threadIdx.x * 8;
        float4 va = *(const float4*)(x + base);
        float4 vb = *(const float4*)(x + base + 4);
        uint4 o;
        o.x = (unsigned int)f2h(va.x) | ((unsigned int)f2h(va.y) << 16);
        o.y = (unsigned int)f2h(va.z) | ((unsigned int)f2h(va.w) << 16);
        o.z = (unsigned int)f2h(vb.x) | ((unsigned int)f2h(vb.y) << 16);
        o.w = (unsigned int)f2h(vb.z) | ((unsigned int)f2h(vb.w) << 16);
        *(uint4*)(xh + base) = o;
    } else {
        int n = blk - FILL_BLOCKS - CONV_BLOCKS;   // 0..127
        int k = threadIdx.x;                       // 0..255
        float v = (k < 128) ? Wself[(size_t)k * D_ + n]
                            : Wnb[(size_t)(k - 128) * D_ + n];
        Bt[(size_t)n * 256 + k] = f2h(v);
    }
}

// 8-slot load+FMA chunk: NO LDS ops inside; packed __hfma2 accumulation (4/slot).
// Masked slots -> hot row 0, m=0 (ejm forced to 0 -> mask f16 bits = 0).
#define GC8(EJ, KO, SB)                                                       \
  {                                                                           \
    uint4 v[8]; __half2 mm[8];                                                \
    _Pragma("unroll")                                                         \
    for (int k = 0; k < 8; ++k) {                                             \
      int ok = (SB) + k < dgg;                                                \
      unsigned int ejm = ok ? EJ[(KO) + k] : 0u;                              \
      int sj = (int)(ejm & 0xffffu);                                          \
      unsigned short mb = (unsigned short)(ejm >> 16);                        \
      mm[k] = __half2half2(__ushort_as_half(mb));                             \
      cs += h2f(mb);                                                          \
      v[k] = *(const uint4*)(xh + ((size_t)sj << 7) + (c8 << 3));             \
    }                                                                         \
    _Pragma("unroll")                                                         \
    for (int k = 0; k < 8; ++k) {                                             \
      const __half2* vp = (const __half2*)&v[k];                              \
      a2[0] = __hfma2(vp[0], mm[k], a2[0]);                                   \
      a2[1] = __hfma2(vp[1], mm[k], a2[1]);                                   \
      a2[2] = __hfma2(vp[2], mm[k], a2[2]);                                   \
      a2[3] = __hfma2(vp[3], mm[k], a2[3]);                                   \
    }                                                                         \
  }

// ---------- fused: hoisted-shfl f16 gather + MFMA _f16 + ReLU + LN + mask ----------
// Grid 8*JB; blk&7 = batch (XCD affinity), blk>>3 = 16-node group within batch.
__global__ __launch_bounds__(256) void fused_k(
    const unsigned short* __restrict__ xh, const int* __restrict__ cnt,
    const unsigned int* __restrict__ entries,
    const unsigned short* __restrict__ Bt,
    const float* __restrict__ bself, const float* __restrict__ bnb,
    const float* __restrict__ gamma, const float* __restrict__ beta,
    const float* __restrict__ nmask, float* __restrict__ out)
{
    __shared__ unsigned short xs[16][LDSP];
    __shared__ unsigned short as[16][LDSP];
    __shared__ float red[4][2][16];

    int t = threadIdx.x;
    int lane = t & 63, wv = t >> 6;
    int b = blockIdx.x & 7;
    int j = blockIdx.x >> 3;               // 0..JB-1
    int i0 = j * 16;
    int g0 = b * N_ + i0;
    int limit = N_ - i0; if (limit > 16) limit = 16;

    int grp = lane >> 4;                   // lane-group: which of the wave's 4 nodes
    int c8  = lane & 15;                   // 16B chunk (8 f16) within the 256B row
    int lanebase = lane & 48;
    int myrow = (wv << 2) + grp;           // 0..15: node row owned by this lane-group

    // Issue gather metadata loads first; latency hides under xs staging.
    int ga = g0 + ((myrow < limit) ? myrow : 0);      // clamped (valid addr)
    int dgr = cnt[ga];
    const unsigned int* ep = entries + ((size_t)ga << 6);
    unsigned int ee0 = ep[c8];             // slots 0..15 (lane c8 holds slot c8)
    unsigned int ee1 = ep[16 + c8];        // slots 16..31 (deg>16 w.p. 0.78)

    // Phase A1: stage own xh rows into LDS (4 rows/wave).
    #pragma unroll
    for (int lr = wv * 4; lr < wv * 4 + 4; ++lr) {
        unsigned int v = 0;
        if (lr < limit)
            v = ((const unsigned int*)(xh + (size_t)(g0 + lr) * D_))[lane];
        ((unsigned int*)&xs[lr][0])[lane] = v;
    }

    // Phase A2: group-parallel gather, bpermutes hoisted in 16-wide batches;
    // packed f16 accumulation (lane (grp,c8) owns elements 8c8..8c8+7).
    int dgg = (myrow < limit) ? ((dgr > CAP) ? CAP : dgr) : 0;

    __half2 a2[4];
    #pragma unroll
    for (int i = 0; i < 4; ++i) a2[i] = __float2half2_rn(0.0f);
    float cs = 0.f;

    unsigned int ej[16];
    #pragma unroll
    for (int k = 0; k < 16; ++k)
        ej[k] = (unsigned int)__shfl((int)ee0, lanebase + k, 64);

    if (0 < dgg) GC8(ej, 0, 0);
    if (8 < dgg) GC8(ej, 8, 8);

    if (__any(dgg > 16)) {                 // batch B: slots 16..31
        #pragma unroll
        for (int k = 0; k < 16; ++k)
            ej[k] = (unsigned int)__shfl((int)ee1, lanebase + k, 64);
        if (16 < dgg) GC8(ej, 0, 16);
        if (24 < dgg) GC8(ej, 8, 24);
    }

    if (__any(dgg > 32)) {                 // rare tail (P ~ 0.4% of waves)
        #pragma unroll 1
        for (int k0 = 32; k0 < CAP; k0 += 8) {
            if (__all(dgg <= k0)) break;
            unsigned int ejt[8];
            #pragma unroll
            for (int kk = 0; kk < 8; ++kk)
                ejt[kk] = ep[k0 + kk];     // group-uniform addr -> broadcast
            if (k0 < dgg) GC8(ejt, 0, k0);
        }
    }

    // cs is uniform within the group (every lane summed every edge's m).
    {
        float inv = 1.0f / fmaxf(cs, 1.0f);
        __half2 ih = __float2half2_rn(inv);
        uint4 o;
        __half2* op2 = (__half2*)&o;
        op2[0] = __hmul2(a2[0], ih);
        op2[1] = __hmul2(a2[1], ih);
        op2[2] = __hmul2(a2[2], ih);
        op2[3] = __hmul2(a2[3], ih);
        *(uint4*)&as[myrow][c8 << 3] = o;   // rows >= limit: dgg=0 -> zeros
    }
    __syncthreads();

    // Phase B: wave wv owns col-tiles 2wv, 2wv+1.
    int quad = lane >> 4;
    int lcol = lane & 15;

    f32x4 acc[2];
    acc[0] = (f32x4)0.0f;
    acc[1] = (f32x4)0.0f;

    #pragma unroll
    for (int kk = 0; kk < 4; ++kk) {
        int kof = kk * 32 + quad * 8;
        f16x8 av = *(const f16x8*)&xs[lcol][kof];
        #pragma unroll
        for (int p = 0; p < 2; ++p) {
            int tt = wv * 2 + p;
            f16x8 bf = *(const f16x8*)(Bt + (size_t)(tt * 16 + lcol) * 256 + kof);
            acc[p] = __builtin_amdgcn_mfma_f32_16x16x32_f16(av, bf, acc[p], 0, 0, 0);
        }
    }
    #pragma unroll
    for (int kk = 0; kk < 4; ++kk) {
        int kof = kk * 32 + quad * 8;
        f16x8 av = *(const f16x8*)&as[lcol][kof];
        #pragma unroll
        for (int p = 0; p < 2; ++p) {
            int tt = wv * 2 + p;
            f16x8 bf = *(const f16x8*)(Bt + (size_t)(tt * 16 + lcol) * 256 + 128 + kof);
            acc[p] = __builtin_amdgcn_mfma_f32_16x16x32_f16(av, bf, acc[p], 0, 0, 0);
        }
    }

    // bias + ReLU; per-wave 32-col LN partials
    float h[2][4];
    float s[4] = {0, 0, 0, 0}, q[4] = {0, 0, 0, 0};
    float gam[2], bet[2];
    #pragma unroll
    for (int p = 0; p < 2; ++p) {
        int col = (wv * 2 + p) * 16 + lcol;
        float bs = bself[col] + bnb[col];
        gam[p] = gamma[col];
        bet[p] = beta[col];
        #pragma unroll
        for (int r = 0; r < 4; ++r) {
            float v = fmaxf(acc[p][r] + bs, 0.0f);
            h[p][r] = v;
            s[r] += v;
            q[r] += v * v;
        }
    }
    #pragma unroll
    for (int r = 0; r < 4; ++r) {
        #pragma unroll
        for (int off = 1; off <= 8; off <<= 1) {
            s[r] += __shfl_xor(s[r], off, 64);
            q[r] += __shfl_xor(q[r], off, 64);
        }
    }
    if (lcol == 0) {
        #pragma unroll
        for (int r = 0; r < 4; ++r) {
            red[wv][0][quad * 4 + r] = s[r];
            red[wv][1][quad * 4 + r] = q[r];
        }
    }
    __syncthreads();

    #pragma unroll
    for (int r = 0; r < 4; ++r) {
        int row = quad * 4 + r;
        int irow = i0 + row;
        if (irow >= N_) continue;
        float S = red[0][0][row] + red[1][0][row] + red[2][0][row] + red[3][0][row];
        float Q = red[0][1][row] + red[1][1][row] + red[2][1][row] + red[3][1][row];
        float mu = S * (1.0f / D_);
        float var = Q * (1.0f / D_) - mu * mu;
        float rin = rsqrtf(fmaxf(var, 0.0f) + EPS_);
        int g = b * N_ + irow;
        float mk = nmask[g];
        float* op = out + (size_t)g * D_;
        #pragma unroll
        for (int p = 0; p < 2; ++p) {
            int col = (wv * 2 + p) * 16 + lcol;
            op[col] = ((h[p][r] - mu) * rin * gam[p] + bet[p]) * mk;
        }
    }
}

extern "C" void kernel_launch(void* const* d_in, const int* in_sizes, int n_in,
                              void* d_out, int out_size, void* d_ws, size_t ws_size,
                              hipStream_t stream)
{
    const float* x     = (const float*)d_in[0];
    const int*   ei    = (const int*)d_in[1];
    const float* nmask = (const float*)d_in[2];
    const float* em    = (const float*)d_in[3];
    const float* Wself = (const float*)d_in[4];
    const float* bself = (const float*)d_in[5];
    const float* Wnb   = (const float*)d_in[6];
    const float* bnb   = (const float*)d_in[7];
    const float* gamma = (const float*)d_in[8];
    const float* beta  = (const float*)d_in[9];
    float* out = (float*)d_out;

    // ws: cnt int[40000] | entries u32[40000*64] (10.24 MB) | Bt f16[128*256]
    //     | xh f16[40000*128] (10.24 MB)   -> ~21 MB total
    int* cnt = (int*)d_ws;
    unsigned int* entries = (unsigned int*)(cnt + NNODES);
    unsigned short* Bt = (unsigned short*)(entries + (size_t)NNODES * CAP);
    unsigned short* xh = Bt + (size_t)128 * 256;                 // 16-aligned

    hipMemsetAsync(cnt, 0, NNODES * sizeof(int), stream);
    fill_k<<<FILL_BLOCKS + CONV_BLOCKS + 128, 256, 0, stream>>>(
        ei, em, cnt, entries, x, xh, Wself, Wnb, Bt);
    fused_k<<<8 * JB, 256, 0, stream>>>(xh, cnt, entries, Bt,
                                        bself, bnb, gamma, beta, nmask, out);
}